// Round 1
// baseline (78.923 us; speedup 1.0000x reference)
//
#include <hip/hip_runtime.h>

// RelativePositionalEncoding:
//   out[b,h,i,j] = sum_d q[b,i,h,d] * T[128 + x[b,j] - x[b,i], h*64+d]
// Strategy: rel takes <=256 values -> per (b,i,h) compute t[r] for all r once
// (lane r holds table row r in 64 VGPRs, reused across TI i-rows), then the
// output row is an LDS gather. Compute drops from 537 -> 269 MFLOP and the
// [B,S,S,E] intermediate is never materialized.

#define S_LEN 512
#define NH 8
#define HD 64
#define EDIM 512
#define TI 16   // i-rows per block; grid = B*NH*(S/TI) = 512 blocks -> 2 blocks/CU

__global__ __launch_bounds__(256) void relpos_kernel(
    const float* __restrict__ q,     // [B, S, H, D]
    const float* __restrict__ et,    // [257, E]
    const int*   __restrict__ x,     // [B, S]
    const int*   __restrict__ maxx_p,
    float*       __restrict__ out)   // [B, H, S, S]
{
    const int tid = threadIdx.x;                 // lane's table row r = tid in [0,256)
    const int per = S_LEN / TI;                  // 32
    const int b   = blockIdx.x / (NH * per);
    const int h   = (blockIdx.x / per) % NH;
    const int i0  = (blockIdx.x % per) * TI;

    const int maxx = maxx_p[0];                  // 128

    // Table row r -> registers (64 floats = 16 float4). Read once per block,
    // L2-served (same 64KB slice shared by all blocks with this h).
    const float4* trow = (const float4*)(et + (size_t)tid * EDIM + h * HD);
    float4 treg[16];
    #pragma unroll
    for (int k = 0; k < 16; ++k) treg[k] = trow[k];

    // x[b, j] for this lane's two output columns, once per block.
    const int xj0 = x[b * S_LEN + tid];
    const int xj1 = x[b * S_LEN + 256 + tid];

    __shared__ float t_lds[2][256];              // double-buffered scores-by-rel

    int p = 0;
    #pragma unroll 1
    for (int ii = 0; ii < TI; ++ii) {
        const int i = i0 + ii;

        // q row address is block-uniform -> scalar (SMEM) loads expected.
        const float4* qrow = (const float4*)(q + (((size_t)b * S_LEN + i) * NH + h) * HD);
        float acc = 0.f;
        #pragma unroll
        for (int k = 0; k < 16; ++k) {
            float4 qv = qrow[k];
            acc += qv.x * treg[k].x + qv.y * treg[k].y
                 + qv.z * treg[k].z + qv.w * treg[k].w;
        }
        t_lds[p][tid] = acc;

        const int xi = x[b * S_LEN + i];         // uniform
        __syncthreads();                          // t_lds[p] complete; also fences
                                                  // prior-iteration reads of buf p^1

        // rel in [1,255] for x in [0,128); &255 keeps LDS access in-bounds.
        const int r0 = (maxx + xj0 - xi) & 255;
        const int r1 = (maxx + xj1 - xi) & 255;
        float* orow = out + (((size_t)b * NH + h) * S_LEN + i) * S_LEN;
        orow[tid]       = t_lds[p][r0];
        orow[tid + 256] = t_lds[p][r1];
        p ^= 1;
    }
}

extern "C" void kernel_launch(void* const* d_in, const int* in_sizes, int n_in,
                              void* d_out, int out_size, void* d_ws, size_t ws_size,
                              hipStream_t stream) {
    const float* q    = (const float*)d_in[0];
    const float* et   = (const float*)d_in[1];
    const int*   x    = (const int*)d_in[2];
    const int*   maxx = (const int*)d_in[3];
    float*       out  = (float*)d_out;

    const int B = in_sizes[2] / S_LEN;           // 2
    dim3 grid(B * NH * (S_LEN / TI));            // 512 blocks
    relpos_kernel<<<grid, 256, 0, stream>>>(q, et, x, maxx, out);
}

// Round 2
// 75.615 us; speedup vs baseline: 1.0437x; 1.0437x over previous
//
#include <hip/hip_runtime.h>

// out[b,h,i,j] = sum_d q[b,i,h,d] * T[128 + x[b,j] - x[b,i], h*64+d]
// rel takes <256 values -> per (b,h,i-tile): lane r keeps table row r (h-slice)
// in 64 VGPRs, computes t[ii][r] for all TI rows in ONE register pass
// (q-tile broadcast from LDS), one barrier, then gather+store.
// vs round 1: 2 barriers/block instead of 17, no global loads in the hot loop,
// 16 independent FMA chains instead of 1.

#define S_LEN 512
#define NH 8
#define HD 64
#define EDIM 512
#define TI 16   // i-rows per block; grid = B*NH*(S/TI) = 512 blocks

__global__ __launch_bounds__(256) void relpos_kernel(
    const float* __restrict__ q,     // [B, S, H, D]
    const float* __restrict__ et,    // [257, E]
    const int*   __restrict__ x,     // [B, S]
    const int*   __restrict__ maxx_p,
    float*       __restrict__ out)   // [B, H, S, S]
{
    const int tid = threadIdx.x;                 // lane's table row r = tid
    const int per = S_LEN / TI;                  // 32
    const int b   = blockIdx.x / (NH * per);
    const int h   = (blockIdx.x / per) % NH;
    const int i0  = (blockIdx.x % per) * TI;

    __shared__ float q_lds[TI * HD];             // 4 KB   q tile
    __shared__ float t_lds[TI][256];             // 16 KB  scores-by-rel
    __shared__ int   xi_lds[TI];

    // --- stage q tile (coalesced: lane -> float4 #tid of the 4KB tile) ---
    {
        const int ii = tid >> 4;
        const int k  = tid & 15;
        const float4 v = *(const float4*)(q + (((size_t)b * S_LEN + i0 + ii) * NH + h) * HD + k * 4);
        *(float4*)(q_lds + tid * 4) = v;
    }
    if (tid < TI) xi_lds[tid] = x[b * S_LEN + i0 + tid];

    // --- table row tid, h-slice -> 64 VGPRs (once per block, reused TI x) ---
    const float4* trow = (const float4*)(et + (size_t)tid * EDIM + h * HD);
    float4 treg[16];
    #pragma unroll
    for (int k = 0; k < 16; ++k) treg[k] = trow[k];

    // lane's two output columns j = 2*tid, 2*tid+1
    const int2 xj = *(const int2*)(x + b * S_LEN + 2 * tid);
    const int maxx = maxx_p[0];

    __syncthreads();                             // q_lds / xi_lds ready

    // --- compute t[ii][tid] for all TI rows, register-resident ---
    float acc[TI];
    #pragma unroll
    for (int ii = 0; ii < TI; ++ii) acc[ii] = 0.f;

    #pragma unroll
    for (int k = 0; k < 16; ++k) {
        const float4 t4 = treg[k];
        #pragma unroll
        for (int ii = 0; ii < TI; ++ii) {        // q4 is a block-uniform LDS broadcast
            const float4 q4 = *(const float4*)(q_lds + ii * HD + k * 4);
            acc[ii] += q4.x * t4.x + q4.y * t4.y + q4.z * t4.z + q4.w * t4.w;
        }
    }
    #pragma unroll
    for (int ii = 0; ii < TI; ++ii) t_lds[ii][tid] = acc[ii];

    __syncthreads();                             // the ONE data barrier

    // --- gather + coalesced float2 stores ---
    float* obase = out + (((size_t)b * NH + h) * S_LEN + i0) * S_LEN;
    #pragma unroll
    for (int ii = 0; ii < TI; ++ii) {
        const int xi = xi_lds[ii];
        const int r0 = (maxx + xj.x - xi) & 255; // rel in [1,255]; mask = bounds safety
        const int r1 = (maxx + xj.y - xi) & 255;
        float2 o;
        o.x = t_lds[ii][r0];
        o.y = t_lds[ii][r1];
        *(float2*)(obase + (size_t)ii * S_LEN + 2 * tid) = o;
    }
}

extern "C" void kernel_launch(void* const* d_in, const int* in_sizes, int n_in,
                              void* d_out, int out_size, void* d_ws, size_t ws_size,
                              hipStream_t stream) {
    const float* q    = (const float*)d_in[0];
    const float* et   = (const float*)d_in[1];
    const int*   x    = (const int*)d_in[2];
    const int*   maxx = (const int*)d_in[3];
    float*       out  = (float*)d_out;

    const int B = in_sizes[2] / S_LEN;           // 2
    dim3 grid(B * NH * (S_LEN / TI));            // 512 blocks
    relpos_kernel<<<grid, 256, 0, stream>>>(q, et, x, maxx, out);
}

// Round 3
// 67.521 us; speedup vs baseline: 1.1689x; 1.1199x over previous
//
#include <hip/hip_runtime.h>

// out[b,h,i,j] = sum_d q[b,i,h,d] * T[128 + x[b,j] - x[b,i], h*64+d]
// Round 3: t[ii][r] = dot(q[ii], T[r]) is a 16x256x64 GEMM per (b,h,i-tile)
// -> 8 mfma_f32_16x16x32_bf16 per wave replaces 1024 v_fmac + 256 LDS
// broadcast reads per lane (operand delivery was the bottleneck, not FLOPs).
// T h-slice + q tile staged to LDS as bf16 with +8-elem row pad (breaks the
// 128B-row-stride bank alias for B-fragment ds_read_b128).

#define S_LEN 512
#define NH 8
#define HD 64
#define EDIM 512
#define TI 16      // i-rows per block; grid = B*NH*(S/TI) = 512 blocks
#define NR 256     // rel values covered
#define TPAD 72    // bf16 elems per padded row (64 + 8)
#define OPAD 257   // t-table row pad (floats)

typedef __attribute__((ext_vector_type(8))) short bf16x8;
typedef __attribute__((ext_vector_type(4))) float f32x4;

__device__ __forceinline__ unsigned short f2bf(float f) {
    union { float f; unsigned u; } v; v.f = f;
    unsigned r = v.u + 0x7fffu + ((v.u >> 16) & 1u);   // RNE
    return (unsigned short)(r >> 16);
}

__global__ __launch_bounds__(256) void relpos_kernel(
    const float* __restrict__ q,     // [B, S, H, D]
    const float* __restrict__ et,    // [257, E]
    const int*   __restrict__ x,     // [B, S]
    const int*   __restrict__ maxx_p,
    float*       __restrict__ out)   // [B, H, S, S]
{
    const int tid = threadIdx.x;
    const int per = S_LEN / TI;                  // 32
    const int b   = blockIdx.x / (NH * per);
    const int h   = (blockIdx.x / per) % NH;
    const int i0  = (blockIdx.x % per) * TI;

    __shared__ unsigned short Tl[NR][TPAD];      // 36 KB  table h-slice, bf16
    __shared__ unsigned short Ql[TI][TPAD];      // 2.25 KB q tile, bf16
    __shared__ float          Ts[TI][OPAD];      // 16.1 KB scores-by-rel
    __shared__ int            xi_s[TI];

    const int row16 = tid >> 4;                  // 0..15
    const int k4    = tid & 15;                  // float4 index within row

    // --- stage table h-slice -> bf16 LDS (coalesced: 16 lanes cover one row) ---
    #pragma unroll
    for (int p = 0; p < 16; ++p) {
        const int r = p * 16 + row16;
        const float4 v = *(const float4*)(et + (size_t)r * EDIM + h * HD + k4 * 4);
        ushort4 u;
        u.x = f2bf(v.x); u.y = f2bf(v.y); u.z = f2bf(v.z); u.w = f2bf(v.w);
        *(ushort4*)&Tl[r][k4 * 4] = u;
    }
    // --- stage q tile -> bf16 LDS ---
    {
        const float4 v = *(const float4*)(q + (((size_t)b * S_LEN + i0 + row16) * NH + h) * HD + k4 * 4);
        ushort4 u;
        u.x = f2bf(v.x); u.y = f2bf(v.y); u.z = f2bf(v.z); u.w = f2bf(v.w);
        *(ushort4*)&Ql[row16][k4 * 4] = u;
    }
    if (tid < TI) xi_s[tid] = x[b * S_LEN + i0 + tid];
    const int2 xj = *(const int2*)(x + b * S_LEN + 2 * tid);   // lane's 2 j-cols
    const int maxx = maxx_p[0];

    __syncthreads();

    // --- MFMA: S[m][r] = sum_d Q[m][d] * T[r][d], m in [0,16), r in [0,256) ---
    // wave w covers r in [w*64, w*64+64): 4 n-tiles x 2 k-steps.
    const int w    = tid >> 6;
    const int l    = tid & 63;
    const int quad = l >> 4;
    const int c    = l & 15;

    // A-operand layout: lane holds A[m = l&15][k = quad*8 + j], j=0..7
    const bf16x8 a0 = *(const bf16x8*)&Ql[c][quad * 8];        // k = 0..31
    const bf16x8 a1 = *(const bf16x8*)&Ql[c][32 + quad * 8];   // k = 32..63

    f32x4 acc[4];
    #pragma unroll
    for (int nt = 0; nt < 4; ++nt) acc[nt] = (f32x4){0.f, 0.f, 0.f, 0.f};

    #pragma unroll
    for (int nt = 0; nt < 4; ++nt) {
        const int r = w * 64 + nt * 16 + c;
        // B-operand: lane holds B[k = quad*8+j][n = l&15] = T[r][k]
        const bf16x8 b0 = *(const bf16x8*)&Tl[r][quad * 8];
        const bf16x8 b1 = *(const bf16x8*)&Tl[r][32 + quad * 8];
        acc[nt] = __builtin_amdgcn_mfma_f32_16x16x32_bf16(a0, b0, acc[nt], 0, 0, 0);
        acc[nt] = __builtin_amdgcn_mfma_f32_16x16x32_bf16(a1, b1, acc[nt], 0, 0, 0);
    }

    // C/D layout: lane l reg v holds D[m = quad*4 + v][n = l&15]
    #pragma unroll
    for (int nt = 0; nt < 4; ++nt) {
        #pragma unroll
        for (int v = 0; v < 4; ++v) {
            Ts[quad * 4 + v][w * 64 + nt * 16 + c] = acc[nt][v];
        }
    }

    __syncthreads();

    // --- gather + coalesced float2 stores ---
    float* obase = out + (((size_t)b * NH + h) * S_LEN + i0) * S_LEN;
    #pragma unroll
    for (int ii = 0; ii < TI; ++ii) {
        const int xi = xi_s[ii];
        const int r0 = (maxx + xj.x - xi) & 255;   // rel in [1,255]; mask = safety
        const int r1 = (maxx + xj.y - xi) & 255;
        float2 o;
        o.x = Ts[ii][r0];
        o.y = Ts[ii][r1];
        *(float2*)(obase + (size_t)ii * S_LEN + 2 * tid) = o;
    }
}

extern "C" void kernel_launch(void* const* d_in, const int* in_sizes, int n_in,
                              void* d_out, int out_size, void* d_ws, size_t ws_size,
                              hipStream_t stream) {
    const float* q    = (const float*)d_in[0];
    const float* et   = (const float*)d_in[1];
    const int*   x    = (const int*)d_in[2];
    const int*   maxx = (const int*)d_in[3];
    float*       out  = (float*)d_out;

    const int B = in_sizes[2] / S_LEN;           // 2
    dim3 grid(B * NH * (S_LEN / TI));            // 512 blocks
    relpos_kernel<<<grid, 256, 0, stream>>>(q, et, x, maxx, out);
}